// Round 1
// baseline (94.795 us; speedup 1.0000x reference)
//
#include <hip/hip_runtime.h>

#define S 32768
#define E 256
#define NB2 512

__device__ __forceinline__ unsigned encMax(float f) {
  unsigned u = __float_as_uint(f);
  return (u & 0x80000000u) ? ~u : (u | 0x80000000u);
}
__device__ __forceinline__ float decMax(unsigned u) {
  return (u & 0x80000000u) ? __uint_as_float(u ^ 0x80000000u) : __uint_as_float(~u);
}

// K1: q_h (per-head, in LDS), kq[h][c] = sum_d Wk[h*64+d][c]*q[h*64+d], c4[h]=bk_h.q_h
// grid 4 (one block per head), block 256
__global__ void mha_k1_proj(const float* __restrict__ x, const float* __restrict__ W,
                            const float* __restrict__ inb, float* __restrict__ kq,
                            float* __restrict__ c4, unsigned* __restrict__ menc) {
  __shared__ __align__(16) float xs[256];
  __shared__ float qh[64];
  const int t = threadIdx.x;
  const int h = blockIdx.x;
  xs[t] = x[t];
  __syncthreads();
  const int lane = t & 63, w = t >> 6;
  const float4 xv = *(const float4*)&xs[lane * 4];
  // wave-per-output: 4 waves x 16 outputs = 64 q values for this head
  for (int k = 0; k < 16; ++k) {
    int eloc = w * 16 + k;
    int e = h * 64 + eloc;
    float4 wv = *(const float4*)&W[(size_t)e * 256 + lane * 4];
    float p = wv.x * xv.x + wv.y * xv.y + wv.z * xv.z + wv.w * xv.w;
#pragma unroll
    for (int m = 1; m < 64; m <<= 1) p += __shfl_xor(p, m);
    if (lane == 0) qh[eloc] = p + inb[e];
  }
  __syncthreads();
  // kq[h][t]: coalesced across t
  float acc = 0.f;
#pragma unroll 8
  for (int d = 0; d < 64; ++d)
    acc += W[(size_t)(E + h * 64 + d) * 256 + t] * qh[d];
  kq[h * 256 + t] = acc;
  if (t == 0) {
    float s = 0.f;
    for (int d = 0; d < 64; ++d) s += inb[E + h * 64 + d] * qh[d];
    c4[h] = s;
    menc[h] = 0u;  // encoding lower bound (-inf -> 0x007FFFFF > 0? no: 0 is < any enc)
  }
}

// K2: scores[s][h] = (x[s].kq[h] + c4[h]) * 0.125; per-head global max via ordered atomicMax
// wave-per-row, grid NB2, block 256
__global__ void mha_k2_scores(const float* __restrict__ x, const float* __restrict__ kq,
                              const float* __restrict__ c4, float* __restrict__ scores,
                              unsigned* __restrict__ menc) {
  const int t = threadIdx.x;
  const int lane = t & 63, wid = t >> 6;
  const float4 kq0 = *(const float4*)&kq[0 * 256 + lane * 4];
  const float4 kq1 = *(const float4*)&kq[1 * 256 + lane * 4];
  const float4 kq2 = *(const float4*)&kq[2 * 256 + lane * 4];
  const float4 kq3 = *(const float4*)&kq[3 * 256 + lane * 4];
  const float c4v = c4[lane & 3];
  float mloc = -3.4e38f;
  const int totalW = gridDim.x * 4;
  for (int row = blockIdx.x * 4 + wid; row < S; row += totalW) {
    float4 xv = *(const float4*)&x[(size_t)row * 256 + lane * 4];
    float p0 = xv.x * kq0.x + xv.y * kq0.y + xv.z * kq0.z + xv.w * kq0.w;
    float p1 = xv.x * kq1.x + xv.y * kq1.y + xv.z * kq1.z + xv.w * kq1.w;
    float p2 = xv.x * kq2.x + xv.y * kq2.y + xv.z * kq2.z + xv.w * kq2.w;
    float p3 = xv.x * kq3.x + xv.y * kq3.y + xv.z * kq3.z + xv.w * kq3.w;
    // 7-shuffle 4-head butterfly: lane ends with full dot for head (lane&3)
    const bool b1 = (lane & 2) != 0;
    float keep0 = b1 ? p2 : p0, send0 = b1 ? p0 : p2;
    keep0 += __shfl_xor(send0, 2);
    float keep1 = b1 ? p3 : p1, send1 = b1 ? p1 : p3;
    keep1 += __shfl_xor(send1, 2);
    const bool b0 = (lane & 1) != 0;
    float v = b0 ? keep1 : keep0, sv = b0 ? keep0 : keep1;
    v += __shfl_xor(sv, 1);
    v += __shfl_xor(v, 4);
    v += __shfl_xor(v, 8);
    v += __shfl_xor(v, 16);
    v += __shfl_xor(v, 32);
    float sc = (v + c4v) * 0.125f;
    if (lane < 4) scores[(size_t)row * 4 + lane] = sc;
    mloc = fmaxf(mloc, sc);
  }
  __shared__ float sm[4][4];
  if (lane < 4) sm[wid][lane] = mloc;
  __syncthreads();
  if (t < 4) {
    float bm = fmaxf(fmaxf(sm[0][t], sm[1][t]), fmaxf(sm[2][t], sm[3][t]));
    atomicMax(&menc[t], encMax(bm));
  }
}

// K3: e = exp(score - m); y-partials per block (thread t owns column t, 4 heads),
// l-partials per block. grid NBY, block 256.
__global__ void mha_k3_expy(const float* __restrict__ x, const float* __restrict__ scores,
                            const unsigned* __restrict__ menc, float* __restrict__ ypart,
                            float* __restrict__ lpart, int rowsPer, int NBY) {
  __shared__ float mld[4];
  __shared__ __align__(16) float eld[256];
  __shared__ float lred[256];
  const int t = threadIdx.x;
  if (t < 4) mld[t] = decMax(menc[t]);
  const int rows0 = blockIdx.x * rowsPer;
  float y0 = 0.f, y1 = 0.f, y2 = 0.f, y3 = 0.f;
  float lsum = 0.f;
  for (int ch = 0; ch < rowsPer; ch += 64) {
    const int nr = min(64, rowsPer - ch);
    __syncthreads();  // also orders mld on first iteration
    if (t < nr * 4) {
      float sc = scores[(size_t)(rows0 + ch) * 4 + t];  // coalesced
      float e = __expf(sc - mld[t & 3]);
      eld[t] = e;
      lsum += e;
    }
    __syncthreads();
    const float* xb = &x[(size_t)(rows0 + ch) * 256 + t];
#pragma unroll 4
    for (int r = 0; r < nr; ++r) {
      float xv = xb[(size_t)r * 256];
      float4 ev = *(const float4*)&eld[r * 4];  // same-address broadcast
      y0 += ev.x * xv; y1 += ev.y * xv; y2 += ev.z * xv; y3 += ev.w * xv;
    }
  }
  float* yp = &ypart[(size_t)blockIdx.x * 1024];
  yp[0 * 256 + t] = y0;
  yp[1 * 256 + t] = y1;
  yp[2 * 256 + t] = y2;
  yp[3 * 256 + t] = y3;
  lred[t] = lsum;
  __syncthreads();
  if (t < 4) {
    float s = 0.f;
    for (int i = 0; i < 64; ++i) s += lred[t + i * 4];
    lpart[t * NBY + blockIdx.x] = s;
  }
}

// K4: y[o] = (1/l[h]) * sum_b ypart[b][o]. grid 32 (block j -> outputs j*32..),
// block 256. l reduced redundantly per block.
__global__ void mha_k4_reduce(const float* __restrict__ ypart, const float* __restrict__ lpart,
                              float* __restrict__ yv, int NBY) {
  __shared__ float lred[256];
  __shared__ float sm2[256];
  const int t = threadIdx.x;
  const int j = blockIdx.x;
  const int h = j >> 3;
  float lp = 0.f;
  for (int i = t; i < NBY; i += 256) lp += lpart[h * NBY + i];
  lred[t] = lp;
  __syncthreads();
  for (int s = 128; s > 0; s >>= 1) {
    if (t < s) lred[t] += lred[t + s];
    __syncthreads();
  }
  const float inv = 1.0f / lred[0];
  const int o = j * 32 + (t & 31);
  float s = 0.f;
  for (int b = t >> 5; b < NBY; b += 8) s += ypart[(size_t)b * 1024 + o];
  sm2[t] = s;
  __syncthreads();
  if (t < 32) {
    float tot = 0.f;
#pragma unroll
    for (int i = 0; i < 8; ++i) tot += sm2[i * 32 + t];
    yv[j * 32 + t] = tot * inv;
  }
}

// K5: ctx = Wv.y + bv (redundant per block), out[e] = Wout.ctx + bout.
// grid 8 (32 outputs each), block 256.
__global__ void mha_k5_out(const float* __restrict__ yv, const float* __restrict__ W,
                           const float* __restrict__ inb, const float* __restrict__ Wout,
                           const float* __restrict__ bout, float* __restrict__ out) {
  __shared__ __align__(16) float ylds[1024];
  __shared__ __align__(16) float ctx[256];
  __shared__ float smo[256];
  const int t = threadIdx.x;
  for (int i = t; i < 1024; i += 256) ylds[i] = yv[i];
  __syncthreads();
  // ctx[t]
  const float4* wr = (const float4*)&W[(size_t)(2 * E + t) * 256];
  const float4* yh = (const float4*)&ylds[(t >> 6) * 256];
  float acc = inb[2 * E + t];
#pragma unroll 8
  for (int k = 0; k < 64; ++k) {
    float4 wv = wr[k];
    float4 yy = yh[k];
    acc += wv.x * yy.x + wv.y * yy.y + wv.z * yy.z + wv.w * yy.w;
  }
  ctx[t] = acc;
  __syncthreads();
  const int e = blockIdx.x * 32 + (t >> 3);
  const int tsub = t & 7;
  const float4* wo = (const float4*)&Wout[(size_t)e * 256 + tsub * 32];
  const float4* cx = (const float4*)&ctx[tsub * 32];
  float a2 = 0.f;
#pragma unroll
  for (int k = 0; k < 8; ++k) {
    float4 wv = wo[k];
    float4 cv = cx[k];
    a2 += wv.x * cv.x + wv.y * cv.y + wv.z * cv.z + wv.w * cv.w;
  }
  smo[t] = a2;
  __syncthreads();
  if (t < 32) {
    float s = bout[blockIdx.x * 32 + t];
#pragma unroll
    for (int i = 0; i < 8; ++i) s += smo[t * 8 + i];
    out[blockIdx.x * 32 + t] = s;
  }
}

extern "C" void kernel_launch(void* const* d_in, const int* in_sizes, int n_in,
                              void* d_out, int out_size, void* d_ws, size_t ws_size,
                              hipStream_t stream) {
  const float* x = (const float*)d_in[0];
  const float* W = (const float*)d_in[1];      // in_proj_weight (768x256)
  const float* inb = (const float*)d_in[2];    // in_proj_bias (768)
  const float* Wout = (const float*)d_in[3];   // out_proj_weight (256x256)
  const float* bout = (const float*)d_in[4];   // out_proj_bias (256)
  float* out = (float*)d_out;
  float* ws = (float*)d_ws;

  // pick NBY (blocks in K3) to fit workspace
  int NBY = 1024;
  for (;;) {
    size_t need = (size_t)(1032 + S * 4 + 4 * NBY) + (size_t)NBY * 1024 + 1024;
    if (need * 4 <= ws_size || NBY <= 32) break;
    NBY >>= 1;
  }
  const int rowsPer = S / NBY;

  float* kq = ws;                               // 1024
  float* c4 = ws + 1024;                        // 4
  unsigned* menc = (unsigned*)(ws + 1028);      // 4
  float* scores = ws + 1032;                    // S*4
  float* lpart = scores + (size_t)S * 4;        // 4*NBY
  float* ypart = lpart + 4 * NBY;               // NBY*1024
  float* yv = ypart + (size_t)NBY * 1024;       // 1024

  mha_k1_proj<<<4, 256, 0, stream>>>(x, W, inb, kq, c4, menc);
  mha_k2_scores<<<NB2, 256, 0, stream>>>(x, kq, c4, scores, menc);
  mha_k3_expy<<<NBY, 256, 0, stream>>>(x, scores, menc, ypart, lpart, rowsPer, NBY);
  mha_k4_reduce<<<32, 256, 0, stream>>>(ypart, lpart, yv, NBY);
  mha_k5_out<<<8, 256, 0, stream>>>(yv, W, inb, Wout, bout, out);
}

// Round 2
// 81.032 us; speedup vs baseline: 1.1699x; 1.1699x over previous
//
#include <hip/hip_runtime.h>

#define S 32768
#define E 256
#define NB2 1024

__device__ __forceinline__ unsigned encMax(float f) {
  unsigned u = __float_as_uint(f);
  return (u & 0x80000000u) ? ~u : (u | 0x80000000u);
}
__device__ __forceinline__ float decMax(unsigned u) {
  return (u & 0x80000000u) ? __uint_as_float(u ^ 0x80000000u) : __uint_as_float(~u);
}

// K1: q_h (per-head), kq[h][c] = sum_d Wk[h*64+d][c]*q[h*64+d], c4[h]=bk_h.q_h
// grid 4 (one block per head), block 256
__global__ void mha_k1_proj(const float* __restrict__ x, const float* __restrict__ W,
                            const float* __restrict__ inb, float* __restrict__ kq,
                            float* __restrict__ c4, unsigned* __restrict__ menc) {
  __shared__ __align__(16) float xs[256];
  __shared__ float qh[64];
  const int t = threadIdx.x;
  const int h = blockIdx.x;
  xs[t] = x[t];
  __syncthreads();
  const int lane = t & 63, w = t >> 6;
  const float4 xv = *(const float4*)&xs[lane * 4];
  for (int k = 0; k < 16; ++k) {
    int eloc = w * 16 + k;
    int e = h * 64 + eloc;
    float4 wv = *(const float4*)&W[(size_t)e * 256 + lane * 4];
    float p = wv.x * xv.x + wv.y * xv.y + wv.z * xv.z + wv.w * xv.w;
#pragma unroll
    for (int m = 1; m < 64; m <<= 1) p += __shfl_xor(p, m);
    if (lane == 0) qh[eloc] = p + inb[e];
  }
  __syncthreads();
  float acc = 0.f;
#pragma unroll 8
  for (int d = 0; d < 64; ++d)
    acc += W[(size_t)(E + h * 64 + d) * 256 + t] * qh[d];
  kq[h * 256 + t] = acc;
  if (t == 0) {
    float s = 0.f;
    for (int d = 0; d < 64; ++d) s += inb[E + h * 64 + d] * qh[d];
    c4[h] = s;
    menc[h] = 0u;
  }
}

// K2: scores[s][h] = (x[s].kq[h] + c4[h]) * 0.125; per-head global max via ordered atomicMax
// contiguous rows per wave, grid NB2, block 256
__global__ void mha_k2_scores(const float* __restrict__ x, const float* __restrict__ kq,
                              const float* __restrict__ c4, float* __restrict__ scores,
                              unsigned* __restrict__ menc) {
  const int t = threadIdx.x;
  const int lane = t & 63, wid = t >> 6;
  const float4 kq0 = *(const float4*)&kq[0 * 256 + lane * 4];
  const float4 kq1 = *(const float4*)&kq[1 * 256 + lane * 4];
  const float4 kq2 = *(const float4*)&kq[2 * 256 + lane * 4];
  const float4 kq3 = *(const float4*)&kq[3 * 256 + lane * 4];
  const float c4v = c4[lane & 3];
  float mloc = -3.4e38f;
  const int rpw = S / (NB2 * 4);  // contiguous rows per wave
  const int r0 = (blockIdx.x * 4 + wid) * rpw;
  for (int row = r0; row < r0 + rpw; ++row) {
    float4 xv = *(const float4*)&x[(size_t)row * 256 + lane * 4];
    float p0 = xv.x * kq0.x + xv.y * kq0.y + xv.z * kq0.z + xv.w * kq0.w;
    float p1 = xv.x * kq1.x + xv.y * kq1.y + xv.z * kq1.z + xv.w * kq1.w;
    float p2 = xv.x * kq2.x + xv.y * kq2.y + xv.z * kq2.z + xv.w * kq2.w;
    float p3 = xv.x * kq3.x + xv.y * kq3.y + xv.z * kq3.z + xv.w * kq3.w;
    const bool b1 = (lane & 2) != 0;
    float keep0 = b1 ? p2 : p0, send0 = b1 ? p0 : p2;
    keep0 += __shfl_xor(send0, 2);
    float keep1 = b1 ? p3 : p1, send1 = b1 ? p1 : p3;
    keep1 += __shfl_xor(send1, 2);
    const bool b0 = (lane & 1) != 0;
    float v = b0 ? keep1 : keep0, sv = b0 ? keep0 : keep1;
    v += __shfl_xor(sv, 1);
    v += __shfl_xor(v, 4);
    v += __shfl_xor(v, 8);
    v += __shfl_xor(v, 16);
    v += __shfl_xor(v, 32);
    float sc = (v + c4v) * 0.125f;
    if (lane < 4) scores[(size_t)row * 4 + lane] = sc;
    mloc = fmaxf(mloc, sc);
  }
  __shared__ float sm[4][4];
  if (lane < 4) sm[wid][lane] = mloc;
  __syncthreads();
  if (t < 4) {
    float bm = fmaxf(fmaxf(sm[0][t], sm[1][t]), fmaxf(sm[2][t], sm[3][t]));
    atomicMax(&menc[t], encMax(bm));
  }
}

// K3: e = exp(score - m); per-block y partials (float4/lane, cross-wave LDS reduce).
// grid NBY, block 256. rowsPer % 64 == 0.
__global__ void mha_k3_expy(const float* __restrict__ x, const float* __restrict__ scores,
                            const unsigned* __restrict__ menc, float* __restrict__ ypart,
                            float* __restrict__ lpart, int rowsPer, int NBY) {
  __shared__ float mld[4];
  __shared__ __align__(16) float eld[256];
  __shared__ float lred[256];
  __shared__ __align__(16) float ylds[4][1024];
  const int t = threadIdx.x;
  const int lane = t & 63, w = t >> 6;
  if (t < 4) mld[t] = decMax(menc[t]);
  const int rows0 = blockIdx.x * rowsPer;
  float4 a0 = {0.f, 0.f, 0.f, 0.f}, a1 = a0, a2 = a0, a3 = a0;
  float lsum = 0.f;
  for (int ch = 0; ch < rowsPer; ch += 64) {
    __syncthreads();  // mld ready (1st iter) / eld consumed (later iters)
    {
      float sc = scores[(size_t)(rows0 + ch) * 4 + t];  // 64 rows x 4 heads, coalesced
      float e = __expf(sc - mld[t & 3]);
      eld[t] = e;
      lsum += e;
    }
    __syncthreads();
    const float* xbase = &x[((size_t)(rows0 + ch)) * 256 + lane * 4];
    for (int r = w; r < 64; r += 4) {
      float4 xv = *(const float4*)&xbase[(size_t)r * 256];
      float4 ev = *(const float4*)&eld[r * 4];  // broadcast
      a0.x += xv.x * ev.x; a0.y += xv.y * ev.x; a0.z += xv.z * ev.x; a0.w += xv.w * ev.x;
      a1.x += xv.x * ev.y; a1.y += xv.y * ev.y; a1.z += xv.z * ev.y; a1.w += xv.w * ev.y;
      a2.x += xv.x * ev.z; a2.y += xv.y * ev.z; a2.z += xv.z * ev.z; a2.w += xv.w * ev.z;
      a3.x += xv.x * ev.w; a3.y += xv.y * ev.w; a3.z += xv.z * ev.w; a3.w += xv.w * ev.w;
    }
  }
  *(float4*)&ylds[w][0 * 256 + lane * 4] = a0;
  *(float4*)&ylds[w][1 * 256 + lane * 4] = a1;
  *(float4*)&ylds[w][2 * 256 + lane * 4] = a2;
  *(float4*)&ylds[w][3 * 256 + lane * 4] = a3;
  lred[t] = lsum;
  __syncthreads();
  float* yp = &ypart[(size_t)blockIdx.x * 1024];
  for (int o = t; o < 1024; o += 256)
    yp[o] = ylds[0][o] + ylds[1][o] + ylds[2][o] + ylds[3][o];
  if (t < 4) {
    float s2 = 0.f;
    for (int i = 0; i < 64; ++i) s2 += lred[t + i * 4];
    lpart[t * NBY + blockIdx.x] = s2;
  }
}

// K4: y[o] = (1/l[h]) * sum_b ypart[b][o]. grid 16 (64 contiguous outputs each), block 256.
__global__ void mha_k4_reduce(const float* __restrict__ ypart, const float* __restrict__ lpart,
                              float* __restrict__ yv, int NBY) {
  __shared__ float linv[4];
  __shared__ float sred[4][64];
  const int t = threadIdx.x;
  const int lane = t & 63, w = t >> 6;
  // wave w reduces l for head w (deterministic fixed-order + shuffle tree)
  {
    float lp = 0.f;
    for (int i = lane; i < NBY; i += 64) lp += lpart[w * NBY + i];
#pragma unroll
    for (int m = 1; m < 64; m <<= 1) lp += __shfl_xor(lp, m);
    if (lane == 0) linv[w] = 1.0f / lp;
  }
  const int o = blockIdx.x * 64 + lane;
  float s = 0.f;
  for (int b = w; b < NBY; b += 4) s += ypart[(size_t)b * 1024 + o];  // 256B coalesced/wave
  sred[w][lane] = s;
  __syncthreads();
  if (w == 0) {
    float tot = sred[0][lane] + sred[1][lane] + sred[2][lane] + sred[3][lane];
    yv[o] = tot * linv[o >> 8];
  }
}

// K5: ctx = Wv.y + bv (redundant per block), out[e] = Wout.ctx + bout.
// grid 8 (32 outputs each), block 256.
__global__ void mha_k5_out(const float* __restrict__ yv, const float* __restrict__ W,
                           const float* __restrict__ inb, const float* __restrict__ Wout,
                           const float* __restrict__ bout, float* __restrict__ out) {
  __shared__ __align__(16) float ylds[1024];
  __shared__ __align__(16) float ctx[256];
  __shared__ float smo[256];
  const int t = threadIdx.x;
  for (int i = t; i < 1024; i += 256) ylds[i] = yv[i];
  __syncthreads();
  const float4* wr = (const float4*)&W[(size_t)(2 * E + t) * 256];
  const float4* yh = (const float4*)&ylds[(t >> 6) * 256];
  float acc = inb[2 * E + t];
#pragma unroll 8
  for (int k = 0; k < 64; ++k) {
    float4 wv = wr[k];
    float4 yy = yh[k];
    acc += wv.x * yy.x + wv.y * yy.y + wv.z * yy.z + wv.w * yy.w;
  }
  ctx[t] = acc;
  __syncthreads();
  const int e = blockIdx.x * 32 + (t >> 3);
  const int tsub = t & 7;
  const float4* wo = (const float4*)&Wout[(size_t)e * 256 + tsub * 32];
  const float4* cx = (const float4*)&ctx[tsub * 32];
  float a2 = 0.f;
#pragma unroll
  for (int k = 0; k < 8; ++k) {
    float4 wv = wo[k];
    float4 cv = cx[k];
    a2 += wv.x * cv.x + wv.y * cv.y + wv.z * cv.z + wv.w * cv.w;
  }
  smo[t] = a2;
  __syncthreads();
  if (t < 32) {
    float s = bout[blockIdx.x * 32 + t];
#pragma unroll
    for (int i = 0; i < 8; ++i) s += smo[t * 8 + i];
    out[blockIdx.x * 32 + t] = s;
  }
}

extern "C" void kernel_launch(void* const* d_in, const int* in_sizes, int n_in,
                              void* d_out, int out_size, void* d_ws, size_t ws_size,
                              hipStream_t stream) {
  const float* x = (const float*)d_in[0];
  const float* W = (const float*)d_in[1];      // in_proj_weight (768x256)
  const float* inb = (const float*)d_in[2];    // in_proj_bias (768)
  const float* Wout = (const float*)d_in[3];   // out_proj_weight (256x256)
  const float* bout = (const float*)d_in[4];   // out_proj_bias (256)
  float* out = (float*)d_out;
  float* ws = (float*)d_ws;

  int NBY = 256;  // one K3 block per CU; ypart = 1 MB (L2-resident)
  for (;;) {
    size_t need = (size_t)(1032 + S * 4 + 4 * NBY) + (size_t)NBY * 1024 + 1024;
    if (need * 4 <= ws_size || NBY <= 64) break;
    NBY >>= 1;
  }
  const int rowsPer = S / NBY;

  float* kq = ws;                               // 1024
  float* c4 = ws + 1024;                        // 4
  unsigned* menc = (unsigned*)(ws + 1028);      // 4
  float* scores = ws + 1032;                    // S*4
  float* lpart = scores + (size_t)S * 4;        // 4*NBY
  float* ypart = lpart + 4 * NBY;               // NBY*1024
  float* yv = ypart + (size_t)NBY * 1024;       // 1024

  mha_k1_proj<<<4, 256, 0, stream>>>(x, W, inb, kq, c4, menc);
  mha_k2_scores<<<NB2, 256, 0, stream>>>(x, kq, c4, scores, menc);
  mha_k3_expy<<<NBY, 256, 0, stream>>>(x, scores, menc, ypart, lpart, rowsPer, NBY);
  mha_k4_reduce<<<16, 256, 0, stream>>>(ypart, lpart, yv, NBY);
  mha_k5_out<<<8, 256, 0, stream>>>(yv, W, inb, Wout, bout, out);
}

// Round 3
// 40.628 us; speedup vs baseline: 2.3333x; 1.9945x over previous
//
#include <hip/hip_runtime.h>

#define S 32768
#define E 256
#define NB 512  // blocks in fused pass; 8 waves x 8 rows each

// K1a: q[e] = Wq[e].x0 + bq[e]. grid 16 (16 outputs each), block 256.
__global__ void mha_k1a_q(const float* __restrict__ x, const float* __restrict__ W,
                          const float* __restrict__ inb, float* __restrict__ q) {
  __shared__ __align__(16) float xs[256];
  const int t = threadIdx.x;
  xs[t] = x[t];
  __syncthreads();
  const int lane = t & 63, w = t >> 6;
  const float4 xv = *(const float4*)&xs[lane * 4];
#pragma unroll
  for (int k = 0; k < 4; ++k) {
    const int e = blockIdx.x * 16 + w * 4 + k;
    float4 wv = *(const float4*)&W[(size_t)e * 256 + lane * 4];
    float p = wv.x * xv.x + wv.y * xv.y + wv.z * xv.z + wv.w * xv.w;
#pragma unroll
    for (int m = 1; m < 64; m <<= 1) p += __shfl_xor(p, m);
    if (lane == 0) q[e] = p + inb[e];
  }
}

// K1b: kq[h][c] = sum_d Wk[h*64+d][c] * q[h*64+d]; c4[h] = bk_h.q_h.
// grid 16 (= 4 heads x 4 column-quarters), block 256 (4 waves split d).
__global__ void mha_k1b_kq(const float* __restrict__ q, const float* __restrict__ W,
                           const float* __restrict__ inb, float* __restrict__ kq,
                           float* __restrict__ c4) {
  __shared__ float qls[64];
  __shared__ float red[4][64];
  const int t = threadIdx.x;
  const int h = blockIdx.x >> 2, qt = blockIdx.x & 3;
  if (t < 64) qls[t] = q[h * 64 + t];
  __syncthreads();
  const int cl = t & 63, ds = t >> 6;
  float acc = 0.f;
#pragma unroll
  for (int d2 = 0; d2 < 16; ++d2) {
    const int d = ds * 16 + d2;
    acc += W[(size_t)(256 + h * 64 + d) * 256 + qt * 64 + cl] * qls[d];
  }
  red[ds][cl] = acc;
  __syncthreads();
  if (ds == 0) kq[h * 256 + qt * 64 + cl] = red[0][cl] + red[1][cl] + red[2][cl] + red[3][cl];
  if (qt == 0 && t < 64) {
    float v = qls[t] * inb[256 + h * 64 + t];
#pragma unroll
    for (int m = 1; m < 64; m <<= 1) v += __shfl_xor(v, m);
    if (t == 0) c4[h] = v;
  }
}

// K2f: single pass over x with online softmax. grid NB, block 512 (8 waves x 8 rows).
// Outputs per block: ypart[blk][1024], mpart[h][blk], lpart[h][blk].
__global__ void __launch_bounds__(512) mha_k2f(const float* __restrict__ x,
                                               const float* __restrict__ kq,
                                               const float* __restrict__ c4,
                                               float* __restrict__ ypart,
                                               float* __restrict__ mpart,
                                               float* __restrict__ lpart) {
  __shared__ float sml[8][4], sll[8][4];
  __shared__ __align__(16) float yls[8][1024];
  const int t = threadIdx.x;
  const int lane = t & 63, w = t >> 6;
  const float4 kq0 = *(const float4*)&kq[0 * 256 + lane * 4];
  const float4 kq1 = *(const float4*)&kq[1 * 256 + lane * 4];
  const float4 kq2 = *(const float4*)&kq[2 * 256 + lane * 4];
  const float4 kq3 = *(const float4*)&kq[3 * 256 + lane * 4];
  const float c4v = c4[lane & 3];

  float m0 = -3.4e38f, m1 = m0, m2 = m0, m3 = m0;
  float l0 = 0.f, l1 = 0.f, l2 = 0.f, l3 = 0.f;
  float4 a0 = {0.f, 0.f, 0.f, 0.f}, a1 = a0, a2 = a0, a3 = a0;

  const int r0 = (blockIdx.x * 8 + w) * 8;
#pragma unroll 2
  for (int r = r0; r < r0 + 8; ++r) {
    float4 xv = *(const float4*)&x[(size_t)r * 256 + lane * 4];
    float p0 = xv.x * kq0.x + xv.y * kq0.y + xv.z * kq0.z + xv.w * kq0.w;
    float p1 = xv.x * kq1.x + xv.y * kq1.y + xv.z * kq1.z + xv.w * kq1.w;
    float p2 = xv.x * kq2.x + xv.y * kq2.y + xv.z * kq2.z + xv.w * kq2.w;
    float p3 = xv.x * kq3.x + xv.y * kq3.y + xv.z * kq3.z + xv.w * kq3.w;
    const bool b1 = (lane & 2) != 0;
    float keep0 = b1 ? p2 : p0, send0 = b1 ? p0 : p2;
    keep0 += __shfl_xor(send0, 2);
    float keep1 = b1 ? p3 : p1, send1 = b1 ? p1 : p3;
    keep1 += __shfl_xor(send1, 2);
    const bool b0 = (lane & 1) != 0;
    float v = b0 ? keep1 : keep0, sv = b0 ? keep0 : keep1;
    v += __shfl_xor(sv, 1);
    v += __shfl_xor(v, 4);
    v += __shfl_xor(v, 8);
    v += __shfl_xor(v, 16);
    v += __shfl_xor(v, 32);
    v = (v + c4v) * 0.125f;
    const float s0 = __shfl(v, 0), s1 = __shfl(v, 1), s2 = __shfl(v, 2), s3 = __shfl(v, 3);
    // online update per head (all values wave-uniform -> uniform branch)
    if (s0 > m0) { float f = __expf(m0 - s0); m0 = s0; l0 *= f; a0.x *= f; a0.y *= f; a0.z *= f; a0.w *= f; }
    { float e = __expf(s0 - m0); l0 += e; a0.x += e * xv.x; a0.y += e * xv.y; a0.z += e * xv.z; a0.w += e * xv.w; }
    if (s1 > m1) { float f = __expf(m1 - s1); m1 = s1; l1 *= f; a1.x *= f; a1.y *= f; a1.z *= f; a1.w *= f; }
    { float e = __expf(s1 - m1); l1 += e; a1.x += e * xv.x; a1.y += e * xv.y; a1.z += e * xv.z; a1.w += e * xv.w; }
    if (s2 > m2) { float f = __expf(m2 - s2); m2 = s2; l2 *= f; a2.x *= f; a2.y *= f; a2.z *= f; a2.w *= f; }
    { float e = __expf(s2 - m2); l2 += e; a2.x += e * xv.x; a2.y += e * xv.y; a2.z += e * xv.z; a2.w += e * xv.w; }
    if (s3 > m3) { float f = __expf(m3 - s3); m3 = s3; l3 *= f; a3.x *= f; a3.y *= f; a3.z *= f; a3.w *= f; }
    { float e = __expf(s3 - m3); l3 += e; a3.x += e * xv.x; a3.y += e * xv.y; a3.z += e * xv.z; a3.w += e * xv.w; }
  }

  if (lane == 0) {
    sml[w][0] = m0; sml[w][1] = m1; sml[w][2] = m2; sml[w][3] = m3;
    sll[w][0] = l0; sll[w][1] = l1; sll[w][2] = l2; sll[w][3] = l3;
  }
  __syncthreads();
  // block max per head (every thread computes; tiny)
  float mb0 = sml[0][0], mb1 = sml[0][1], mb2 = sml[0][2], mb3 = sml[0][3];
#pragma unroll
  for (int i = 1; i < 8; ++i) {
    mb0 = fmaxf(mb0, sml[i][0]); mb1 = fmaxf(mb1, sml[i][1]);
    mb2 = fmaxf(mb2, sml[i][2]); mb3 = fmaxf(mb3, sml[i][3]);
  }
  const float f0 = __expf(m0 - mb0), f1 = __expf(m1 - mb1);
  const float f2 = __expf(m2 - mb2), f3 = __expf(m3 - mb3);
  float4 w0 = {a0.x * f0, a0.y * f0, a0.z * f0, a0.w * f0};
  float4 w1 = {a1.x * f1, a1.y * f1, a1.z * f1, a1.w * f1};
  float4 w2 = {a2.x * f2, a2.y * f2, a2.z * f2, a2.w * f2};
  float4 w3 = {a3.x * f3, a3.y * f3, a3.z * f3, a3.w * f3};
  *(float4*)&yls[w][0 * 256 + lane * 4] = w0;
  *(float4*)&yls[w][1 * 256 + lane * 4] = w1;
  *(float4*)&yls[w][2 * 256 + lane * 4] = w2;
  *(float4*)&yls[w][3 * 256 + lane * 4] = w3;
  __syncthreads();
  if (t < 4) {
    float mb = sml[0][t];
#pragma unroll
    for (int i = 1; i < 8; ++i) mb = fmaxf(mb, sml[i][t]);
    float lb = 0.f;
#pragma unroll
    for (int i = 0; i < 8; ++i) lb += sll[i][t] * __expf(sml[i][t] - mb);
    mpart[t * NB + blockIdx.x] = mb;
    lpart[t * NB + blockIdx.x] = lb;
  }
  float* yp = &ypart[(size_t)blockIdx.x * 1024];
  for (int o = t; o < 1024; o += 512) {
    float s = yls[0][o] + yls[1][o] + yls[2][o] + yls[3][o] +
              yls[4][o] + yls[5][o] + yls[6][o] + yls[7][o];
    yp[o] = s;
  }
}

// K3r: global rescale-reduce. grid 16 (64 outputs each, single head per block), block 256.
__global__ void mha_k3r(const float* __restrict__ ypart, const float* __restrict__ mpart,
                        const float* __restrict__ lpart, float* __restrict__ yv) {
  __shared__ float mred[256];
  __shared__ float lredl[256];
  __shared__ float scales[NB];
  __shared__ float sred[4][64];
  __shared__ float mg_s, linv_s;
  const int t = threadIdx.x;
  const int h = blockIdx.x >> 2;
  // global max for head h
  float mm = fmaxf(mpart[h * NB + t], mpart[h * NB + t + 256]);
  mred[t] = mm;
  __syncthreads();
  for (int s = 128; s > 0; s >>= 1) {
    if (t < s) mred[t] = fmaxf(mred[t], mred[t + s]);
    __syncthreads();
  }
  if (t == 0) mg_s = mred[0];
  __syncthreads();
  const float mg = mg_s;
  // scales + l sum
  float lp = 0.f;
#pragma unroll
  for (int i = t; i < NB; i += 256) {
    float sc = __expf(mpart[h * NB + i] - mg);
    scales[i] = sc;
    lp += lpart[h * NB + i] * sc;
  }
  lredl[t] = lp;
  __syncthreads();
  for (int s = 128; s > 0; s >>= 1) {
    if (t < s) lredl[t] += lredl[t + s];
    __syncthreads();
  }
  if (t == 0) linv_s = 1.0f / lredl[0];
  __syncthreads();
  const float inv = linv_s;
  const int lane = t & 63, w = t >> 6;
  const int o = blockIdx.x * 64 + lane;
  float s = 0.f;
  for (int k = 0; k < 8; ++k) {
    float tmp[16];
#pragma unroll
    for (int j = 0; j < 16; ++j) {
      const int b = w + 4 * (k * 16 + j);
      tmp[j] = ypart[(size_t)b * 1024 + o] * scales[b];
    }
#pragma unroll
    for (int j = 0; j < 16; ++j) s += tmp[j];
  }
  sred[w][lane] = s;
  __syncthreads();
  if (w == 0) yv[o] = (sred[0][lane] + sred[1][lane] + sred[2][lane] + sred[3][lane]) * inv;
}

// K5: ctx = Wv.y + bv (redundant per block), out[e] = Wout.ctx + bout.
// grid 8 (32 outputs each), block 256.
__global__ void mha_k5_out(const float* __restrict__ yv, const float* __restrict__ W,
                           const float* __restrict__ inb, const float* __restrict__ Wout,
                           const float* __restrict__ bout, float* __restrict__ out) {
  __shared__ __align__(16) float ylds[1024];
  __shared__ __align__(16) float ctx[256];
  __shared__ float smo[256];
  const int t = threadIdx.x;
  for (int i = t; i < 1024; i += 256) ylds[i] = yv[i];
  __syncthreads();
  const float4* wr = (const float4*)&W[(size_t)(2 * E + t) * 256];
  const float4* yh = (const float4*)&ylds[(t >> 6) * 256];
  float acc = inb[2 * E + t];
#pragma unroll 8
  for (int k = 0; k < 64; ++k) {
    float4 wv = wr[k];
    float4 yy = yh[k];
    acc += wv.x * yy.x + wv.y * yy.y + wv.z * yy.z + wv.w * yy.w;
  }
  ctx[t] = acc;
  __syncthreads();
  const int e = blockIdx.x * 32 + (t >> 3);
  const int tsub = t & 7;
  const float4* wo = (const float4*)&Wout[(size_t)e * 256 + tsub * 32];
  const float4* cx = (const float4*)&ctx[tsub * 32];
  float a2 = 0.f;
#pragma unroll
  for (int k = 0; k < 8; ++k) {
    float4 wv = wo[k];
    float4 cv = cx[k];
    a2 += wv.x * cv.x + wv.y * cv.y + wv.z * cv.z + wv.w * cv.w;
  }
  smo[t] = a2;
  __syncthreads();
  if (t < 32) {
    float s = bout[blockIdx.x * 32 + t];
#pragma unroll
    for (int i = 0; i < 8; ++i) s += smo[t * 8 + i];
    out[blockIdx.x * 32 + t] = s;
  }
}

extern "C" void kernel_launch(void* const* d_in, const int* in_sizes, int n_in,
                              void* d_out, int out_size, void* d_ws, size_t ws_size,
                              hipStream_t stream) {
  const float* x = (const float*)d_in[0];
  const float* W = (const float*)d_in[1];      // in_proj_weight (768x256)
  const float* inb = (const float*)d_in[2];    // in_proj_bias (768)
  const float* Wout = (const float*)d_in[3];   // out_proj_weight (256x256)
  const float* bout = (const float*)d_in[4];   // out_proj_bias (256)
  float* out = (float*)d_out;
  float* ws = (float*)d_ws;

  float* q = ws;                                 // 256
  float* c4 = ws + 256;                          // 4
  float* kq = ws + 320;                          // 1024 (16B aligned)
  float* mpart = ws + 1344;                      // 4*NB = 2048
  float* lpart = ws + 3392;                      // 2048
  float* ypart = ws + 5440;                      // NB*1024 = 524288
  float* yv = ypart + (size_t)NB * 1024;         // 1024

  mha_k1a_q<<<16, 256, 0, stream>>>(x, W, inb, q);
  mha_k1b_kq<<<16, 256, 0, stream>>>(q, W, inb, kq, c4);
  mha_k2f<<<NB, 512, 0, stream>>>(x, kq, c4, ypart, mpart, lpart);
  mha_k3r<<<16, 256, 0, stream>>>(ypart, mpart, lpart, yv);
  mha_k5_out<<<8, 256, 0, stream>>>(yv, W, inb, Wout, bout, out);
}

// Round 4
// 40.452 us; speedup vs baseline: 2.3434x; 1.0044x over previous
//
#include <hip/hip_runtime.h>

#define S 32768
#define E 256
#define NB 512  // blocks in fused pass; 8 waves x 8 rows each

// K1f: blocks 0..15: q_h (LDS-only, redundant per (h,qt)), kq quarter, c4.
//      blocks 16..79: M2[h][e][c] = sum_d Wout[e][h*64+d] * Wv[h*64+d][c]  (64 blocks)
__global__ void mha_k1f(const float* __restrict__ x, const float* __restrict__ W,
                        const float* __restrict__ inb, const float* __restrict__ Wout,
                        float* __restrict__ kq, float* __restrict__ c4,
                        float* __restrict__ M2) {
  const int t = threadIdx.x;
  if (blockIdx.x < 16) {
    __shared__ __align__(16) float xs[256];
    __shared__ float qls[64];
    __shared__ float red[4][64];
    const int h = blockIdx.x >> 2, qt = blockIdx.x & 3;
    xs[t] = x[t];
    __syncthreads();
    const int lane = t & 63, w = t >> 6;
    const float4 xv = *(const float4*)&xs[lane * 4];
#pragma unroll
    for (int k = 0; k < 16; ++k) {
      const int eloc = w * 16 + k;
      const int row = h * 64 + eloc;
      float4 wv = *(const float4*)&W[(size_t)row * 256 + lane * 4];
      float p = wv.x * xv.x + wv.y * xv.y + wv.z * xv.z + wv.w * xv.w;
#pragma unroll
      for (int m = 1; m < 64; m <<= 1) p += __shfl_xor(p, m);
      if (lane == 0) qls[eloc] = p + inb[row];
    }
    __syncthreads();
    const int cl = t & 63, ds = t >> 6;
    float acc = 0.f;
#pragma unroll
    for (int d2 = 0; d2 < 16; ++d2) {
      const int d = ds * 16 + d2;
      acc += W[(size_t)(256 + h * 64 + d) * 256 + qt * 64 + cl] * qls[d];
    }
    red[ds][cl] = acc;
    __syncthreads();
    if (ds == 0)
      kq[h * 256 + qt * 64 + cl] = red[0][cl] + red[1][cl] + red[2][cl] + red[3][cl];
    if (qt == 0 && t < 64) {
      float v = qls[t] * inb[256 + h * 64 + t];
#pragma unroll
      for (int m = 1; m < 64; m <<= 1) v += __shfl_xor(v, m);
      if (t == 0) c4[h] = v;
    }
  } else {
    // M2 block: b in 0..63 -> head h = b>>4, e-tile e0 = (b&15)*16
    __shared__ float wout_t[16][64];
    const int b = blockIdx.x - 16;
    const int h = b >> 4, e0 = (b & 15) * 16;
    for (int i = t; i < 1024; i += 256) {
      const int e = i >> 6, d = i & 63;
      wout_t[e][d] = Wout[(size_t)(e0 + e) * 256 + h * 64 + d];
    }
    __syncthreads();
    const int c = t;
    float acc[16];
#pragma unroll
    for (int e = 0; e < 16; ++e) acc[e] = 0.f;
#pragma unroll 4
    for (int d = 0; d < 64; ++d) {
      const float wv = W[(size_t)(512 + h * 64 + d) * 256 + c];
#pragma unroll
      for (int e = 0; e < 16; ++e) acc[e] += wv * wout_t[e][d];
    }
#pragma unroll
    for (int e = 0; e < 16; ++e)
      M2[(size_t)(e0 + e) * 1024 + h * 256 + c] = acc[e];
  }
}

// K2f: single pass over x with online softmax. grid NB, block 512 (8 waves x 8 rows).
__global__ void __launch_bounds__(512) mha_k2f(const float* __restrict__ x,
                                               const float* __restrict__ kq,
                                               const float* __restrict__ c4,
                                               float* __restrict__ ypart,
                                               float* __restrict__ mpart,
                                               float* __restrict__ lpart) {
  __shared__ float sml[8][4], sll[8][4];
  __shared__ __align__(16) float yls[8][1024];
  const int t = threadIdx.x;
  const int lane = t & 63, w = t >> 6;
  const float4 kq0 = *(const float4*)&kq[0 * 256 + lane * 4];
  const float4 kq1 = *(const float4*)&kq[1 * 256 + lane * 4];
  const float4 kq2 = *(const float4*)&kq[2 * 256 + lane * 4];
  const float4 kq3 = *(const float4*)&kq[3 * 256 + lane * 4];
  const float c4v = c4[lane & 3];

  float m0 = -3.4e38f, m1 = m0, m2 = m0, m3 = m0;
  float l0 = 0.f, l1 = 0.f, l2 = 0.f, l3 = 0.f;
  float4 a0 = {0.f, 0.f, 0.f, 0.f}, a1 = a0, a2 = a0, a3 = a0;

  const int r0 = (blockIdx.x * 8 + w) * 8;
#pragma unroll 2
  for (int r = r0; r < r0 + 8; ++r) {
    float4 xv = *(const float4*)&x[(size_t)r * 256 + lane * 4];
    float p0 = xv.x * kq0.x + xv.y * kq0.y + xv.z * kq0.z + xv.w * kq0.w;
    float p1 = xv.x * kq1.x + xv.y * kq1.y + xv.z * kq1.z + xv.w * kq1.w;
    float p2 = xv.x * kq2.x + xv.y * kq2.y + xv.z * kq2.z + xv.w * kq2.w;
    float p3 = xv.x * kq3.x + xv.y * kq3.y + xv.z * kq3.z + xv.w * kq3.w;
    const bool b1 = (lane & 2) != 0;
    float keep0 = b1 ? p2 : p0, send0 = b1 ? p0 : p2;
    keep0 += __shfl_xor(send0, 2);
    float keep1 = b1 ? p3 : p1, send1 = b1 ? p1 : p3;
    keep1 += __shfl_xor(send1, 2);
    const bool b0 = (lane & 1) != 0;
    float v = b0 ? keep1 : keep0, sv = b0 ? keep0 : keep1;
    v += __shfl_xor(sv, 1);
    v += __shfl_xor(v, 4);
    v += __shfl_xor(v, 8);
    v += __shfl_xor(v, 16);
    v += __shfl_xor(v, 32);
    v = (v + c4v) * 0.125f;
    const float s0 = __shfl(v, 0), s1 = __shfl(v, 1), s2 = __shfl(v, 2), s3 = __shfl(v, 3);
    if (s0 > m0) { float f = __expf(m0 - s0); m0 = s0; l0 *= f; a0.x *= f; a0.y *= f; a0.z *= f; a0.w *= f; }
    { float e = __expf(s0 - m0); l0 += e; a0.x += e * xv.x; a0.y += e * xv.y; a0.z += e * xv.z; a0.w += e * xv.w; }
    if (s1 > m1) { float f = __expf(m1 - s1); m1 = s1; l1 *= f; a1.x *= f; a1.y *= f; a1.z *= f; a1.w *= f; }
    { float e = __expf(s1 - m1); l1 += e; a1.x += e * xv.x; a1.y += e * xv.y; a1.z += e * xv.z; a1.w += e * xv.w; }
    if (s2 > m2) { float f = __expf(m2 - s2); m2 = s2; l2 *= f; a2.x *= f; a2.y *= f; a2.z *= f; a2.w *= f; }
    { float e = __expf(s2 - m2); l2 += e; a2.x += e * xv.x; a2.y += e * xv.y; a2.z += e * xv.z; a2.w += e * xv.w; }
    if (s3 > m3) { float f = __expf(m3 - s3); m3 = s3; l3 *= f; a3.x *= f; a3.y *= f; a3.z *= f; a3.w *= f; }
    { float e = __expf(s3 - m3); l3 += e; a3.x += e * xv.x; a3.y += e * xv.y; a3.z += e * xv.z; a3.w += e * xv.w; }
  }

  if (lane == 0) {
    sml[w][0] = m0; sml[w][1] = m1; sml[w][2] = m2; sml[w][3] = m3;
    sll[w][0] = l0; sll[w][1] = l1; sll[w][2] = l2; sll[w][3] = l3;
  }
  __syncthreads();
  float mb0 = sml[0][0], mb1 = sml[0][1], mb2 = sml[0][2], mb3 = sml[0][3];
#pragma unroll
  for (int i = 1; i < 8; ++i) {
    mb0 = fmaxf(mb0, sml[i][0]); mb1 = fmaxf(mb1, sml[i][1]);
    mb2 = fmaxf(mb2, sml[i][2]); mb3 = fmaxf(mb3, sml[i][3]);
  }
  const float f0 = __expf(m0 - mb0), f1 = __expf(m1 - mb1);
  const float f2 = __expf(m2 - mb2), f3 = __expf(m3 - mb3);
  float4 w0 = {a0.x * f0, a0.y * f0, a0.z * f0, a0.w * f0};
  float4 w1 = {a1.x * f1, a1.y * f1, a1.z * f1, a1.w * f1};
  float4 w2 = {a2.x * f2, a2.y * f2, a2.z * f2, a2.w * f2};
  float4 w3 = {a3.x * f3, a3.y * f3, a3.z * f3, a3.w * f3};
  *(float4*)&yls[w][0 * 256 + lane * 4] = w0;
  *(float4*)&yls[w][1 * 256 + lane * 4] = w1;
  *(float4*)&yls[w][2 * 256 + lane * 4] = w2;
  *(float4*)&yls[w][3 * 256 + lane * 4] = w3;
  __syncthreads();
  if (t < 4) {
    float mb = sml[0][t];
#pragma unroll
    for (int i = 1; i < 8; ++i) mb = fmaxf(mb, sml[i][t]);
    float lb = 0.f;
#pragma unroll
    for (int i = 0; i < 8; ++i) lb += sll[i][t] * __expf(sml[i][t] - mb);
    mpart[t * NB + blockIdx.x] = mb;
    lpart[t * NB + blockIdx.x] = lb;
  }
  float* yp = &ypart[(size_t)blockIdx.x * 1024];
  for (int o = t; o < 1024; o += 512) {
    float s = yls[0][o] + yls[1][o] + yls[2][o] + yls[3][o] +
              yls[4][o] + yls[5][o] + yls[6][o] + yls[7][o];
    yp[o] = s;
  }
}

// K3r: global rescale-reduce -> yv (already scaled by 1/l per head).
// grid 16 (64 outputs each), block 256.
__global__ void mha_k3r(const float* __restrict__ ypart, const float* __restrict__ mpart,
                        const float* __restrict__ lpart, float* __restrict__ yv) {
  __shared__ float mred[256];
  __shared__ float lredl[256];
  __shared__ float scales[NB];
  __shared__ float sred[4][64];
  __shared__ float mg_s, linv_s;
  const int t = threadIdx.x;
  const int h = blockIdx.x >> 2;
  float mm = fmaxf(mpart[h * NB + t], mpart[h * NB + t + 256]);
  mred[t] = mm;
  __syncthreads();
  for (int s = 128; s > 0; s >>= 1) {
    if (t < s) mred[t] = fmaxf(mred[t], mred[t + s]);
    __syncthreads();
  }
  if (t == 0) mg_s = mred[0];
  __syncthreads();
  const float mg = mg_s;
  float lp = 0.f;
#pragma unroll
  for (int i = t; i < NB; i += 256) {
    float sc = __expf(mpart[h * NB + i] - mg);
    scales[i] = sc;
    lp += lpart[h * NB + i] * sc;
  }
  lredl[t] = lp;
  __syncthreads();
  for (int s = 128; s > 0; s >>= 1) {
    if (t < s) lredl[t] += lredl[t + s];
    __syncthreads();
  }
  if (t == 0) linv_s = 1.0f / lredl[0];
  __syncthreads();
  const float inv = linv_s;
  const int lane = t & 63, w = t >> 6;
  const int o = blockIdx.x * 64 + lane;
  float s = 0.f;
  for (int k = 0; k < 8; ++k) {
    float tmp[16];
#pragma unroll
    for (int j = 0; j < 16; ++j) {
      const int b = w + 4 * (k * 16 + j);
      tmp[j] = ypart[(size_t)b * 1024 + o] * scales[b];
    }
#pragma unroll
    for (int j = 0; j < 16; ++j) s += tmp[j];
  }
  sred[w][lane] = s;
  __syncthreads();
  if (w == 0) yv[o] = (sred[0][lane] + sred[1][lane] + sred[2][lane] + sred[3][lane]) * inv;
}

// K4o: out[e] = M2flat[e].yv + Wout[e].bv + bout[e]. grid 16 (16 outputs each), block 256.
__global__ void mha_k4o(const float* __restrict__ M2, const float* __restrict__ yv,
                        const float* __restrict__ Wout, const float* __restrict__ inb,
                        const float* __restrict__ bout, float* __restrict__ out) {
  __shared__ __align__(16) float yls[1024];
  __shared__ __align__(16) float bvls[256];
  __shared__ float smo[256];
  const int t = threadIdx.x;
  for (int i = t; i < 1024; i += 256) yls[i] = yv[i];
  if (t < 256) bvls[t] = inb[512 + t];
  __syncthreads();
  const int og = t >> 4, seg = t & 15;
  const int e = blockIdx.x * 16 + og;
  float acc = 0.f;
  const float4* m4 = (const float4*)&M2[(size_t)e * 1024 + seg * 64];
  const float4* y4 = (const float4*)&yls[seg * 64];
#pragma unroll
  for (int j = 0; j < 16; ++j) {
    float4 mv = m4[j];
    float4 yy = y4[j];
    acc += mv.x * yy.x + mv.y * yy.y + mv.z * yy.z + mv.w * yy.w;
  }
  if (seg < 4) {
    const float4* w4 = (const float4*)&Wout[(size_t)e * 256 + seg * 64];
    const float4* b4 = (const float4*)&bvls[seg * 64];
#pragma unroll
    for (int j = 0; j < 16; ++j) {
      float4 wv = w4[j];
      float4 bb = b4[j];
      acc += wv.x * bb.x + wv.y * bb.y + wv.z * bb.z + wv.w * bb.w;
    }
  }
  smo[t] = acc;
  __syncthreads();
  if (t < 16) {
    float s = bout[blockIdx.x * 16 + t];
#pragma unroll
    for (int i = 0; i < 16; ++i) s += smo[t * 16 + i];
    out[blockIdx.x * 16 + t] = s;
  }
}

extern "C" void kernel_launch(void* const* d_in, const int* in_sizes, int n_in,
                              void* d_out, int out_size, void* d_ws, size_t ws_size,
                              hipStream_t stream) {
  const float* x = (const float*)d_in[0];
  const float* W = (const float*)d_in[1];      // in_proj_weight (768x256)
  const float* inb = (const float*)d_in[2];    // in_proj_bias (768)
  const float* Wout = (const float*)d_in[3];   // out_proj_weight (256x256)
  const float* bout = (const float*)d_in[4];   // out_proj_bias (256)
  float* out = (float*)d_out;
  float* ws = (float*)d_ws;

  float* c4 = ws;                                // 4 (+pad to 64)
  float* kq = ws + 64;                           // 1024
  float* mpart = ws + 1088;                      // 2048
  float* lpart = ws + 3136;                      // 2048
  float* yv = ws + 5184;                         // 1024
  float* M2 = ws + 6208;                         // 256*1024 = 262144
  float* ypart = ws + 268352;                    // NB*1024 = 524288

  mha_k1f<<<80, 256, 0, stream>>>(x, W, inb, Wout, kq, c4, M2);
  mha_k2f<<<NB, 512, 0, stream>>>(x, kq, c4, ypart, mpart, lpart);
  mha_k3r<<<16, 256, 0, stream>>>(ypart, mpart, lpart, yv);
  mha_k4o<<<16, 256, 0, stream>>>(M2, yv, Wout, inb, bout, out);
}